// Round 3
// baseline (203.511 us; speedup 1.0000x reference)
//
#include <hip/hip_runtime.h>

#define IMG_W 512
#define IMG_H 512
#define BATCH 64
#define ROWS_PER_WAVE 8
#define WAVES_PER_BLOCK 4
#define ROWS_PER_BLOCK (ROWS_PER_WAVE * WAVES_PER_BLOCK)  // 32
#define SLABS (IMG_H / ROWS_PER_BLOCK)                    // 16
#define NBLOCKS (BATCH * SLABS)                           // 1024
#define NPIX (BATCH * IMG_W * IMG_H)

__device__ __forceinline__ float fast_sqrtf(float x) {
    return __builtin_amdgcn_sqrtf(x);
}

// Row-streaming Sobel: no LDS staging. One wave = 8 full rows; lane = 8-px
// strip (64 lanes x 8 px = 512 = image width). 3-row rolling raw window in
// registers; x-halo via 2 shfls/row/array; y-halo re-read from global (L2).
// VGPR ~110 -> launch_bounds(256,4) caps at 128, 16 waves/CU.
__global__ __launch_bounds__(256, 4) void sobel_loss_kernel(
    const float* __restrict__ yp, const float* __restrict__ yt,
    float* __restrict__ bsums)
{
    __shared__ float wred[WAVES_PER_BLOCK];

    const int tid  = threadIdx.x;
    const int lane = tid & 63;
    const int wv   = tid >> 6;
    const int bid  = blockIdx.x;
    const int b    = bid >> 4;            // image index (16 slabs/image)
    const int slab = bid & (SLABS - 1);
    const int y0   = slab * ROWS_PER_BLOCK + wv * ROWS_PER_WAVE;
    const int x0   = lane << 3;           // cols x0..x0+7

    const float* __restrict__ imgp = yp + (size_t)b * (IMG_W * IMG_H);
    const float* __restrict__ imgt = yt + (size_t)b * (IMG_W * IMG_H);

    // rolling raw rows: cols x0-1 .. x0+8 (10 wide) for both inputs
    float hp[3][10], ht[3][10];

    auto load_row = [&](int slot, int y) {
        float4 ap = {0.f, 0.f, 0.f, 0.f}, bp = {0.f, 0.f, 0.f, 0.f};
        float4 at = {0.f, 0.f, 0.f, 0.f}, bt = {0.f, 0.f, 0.f, 0.f};
        if (y >= 0 && y < IMG_H) {                     // wave-uniform branch
            const float* rp = imgp + (size_t)y * IMG_W + x0;
            const float* rt = imgt + (size_t)y * IMG_W + x0;
            ap = *(const float4*)rp;
            bp = *(const float4*)(rp + 4);
            at = *(const float4*)rt;
            bt = *(const float4*)(rt + 4);
        }
        // x-halo from neighbor lanes; image edge -> 0 ('SAME' zero padding)
        float lp = __shfl_up(bp.w, 1, 64);
        float rp_ = __shfl_down(ap.x, 1, 64);
        float lt = __shfl_up(bt.w, 1, 64);
        float rt_ = __shfl_down(at.x, 1, 64);
        if (lane == 0)  { lp = 0.f; lt = 0.f; }
        if (lane == 63) { rp_ = 0.f; rt_ = 0.f; }
        hp[slot][0] = lp;   ht[slot][0] = lt;
        hp[slot][1] = ap.x; hp[slot][2] = ap.y; hp[slot][3] = ap.z; hp[slot][4] = ap.w;
        hp[slot][5] = bp.x; hp[slot][6] = bp.y; hp[slot][7] = bp.z; hp[slot][8] = bp.w;
        ht[slot][1] = at.x; ht[slot][2] = at.y; ht[slot][3] = at.z; ht[slot][4] = at.w;
        ht[slot][5] = bt.x; ht[slot][6] = bt.y; ht[slot][7] = bt.z; ht[slot][8] = bt.w;
        hp[slot][9] = rp_;  ht[slot][9] = rt_;
    };

    load_row(0, y0 - 1);
    load_row(1, y0);

    float lsum = 0.f;
#pragma unroll
    for (int i = 0; i < ROWS_PER_WAVE; ++i) {
        const int s0 = i % 3, s1 = (i + 1) % 3, s2 = (i + 2) % 3;
        load_row(s2, y0 + 1 + i);

        // vertical 1-2-1 column sums over the 10 columns
        float cp[10], ct[10];
#pragma unroll
        for (int k = 0; k < 10; ++k) {
            cp[k] = fmaf(2.f, hp[s1][k], hp[s0][k]) + hp[s2][k];
            ct[k] = fmaf(2.f, ht[s1][k], ht[s0][k]) + ht[s2][k];
        }
#pragma unroll
        for (int j = 0; j < 8; ++j) {
            // horizontal 1-2-1 sums of top/bottom raw rows -> gh
            float tp  = fmaf(2.f, hp[s2][j + 1], hp[s2][j]) + hp[s2][j + 2];
            float bp_ = fmaf(2.f, hp[s0][j + 1], hp[s0][j]) + hp[s0][j + 2];
            float ghp = tp - bp_;
            float gvp = cp[j + 2] - cp[j];
            float magp = fast_sqrtf(fmaf(gvp, gvp, fmaf(ghp, ghp, 1e-18f)));

            float tt  = fmaf(2.f, ht[s2][j + 1], ht[s2][j]) + ht[s2][j + 2];
            float bt_ = fmaf(2.f, ht[s0][j + 1], ht[s0][j]) + ht[s0][j + 2];
            float ght = tt - bt_;
            float gvt = ct[j + 2] - ct[j];
            float magt = fast_sqrtf(fmaf(gvt, gvt, fmaf(ght, ght, 1e-18f)));

            // reference: sqrt(d^2 + 1e-18) * (d^2 != 0) == |d| to <1e-9 abs
            lsum += fabsf(magt - magp);
        }
    }

    // ---- Block reduction ----
#pragma unroll
    for (int off = 32; off > 0; off >>= 1)
        lsum += __shfl_down(lsum, off, 64);
    if (lane == 0) wred[wv] = lsum;
    __syncthreads();
    if (tid == 0)
        bsums[bid] = wred[0] + wred[1] + wred[2] + wred[3];
}

__global__ __launch_bounds__(256) void reduce_final(
    const float* __restrict__ bsums, float* __restrict__ out)
{
    __shared__ float wred[4];
    const int tid = threadIdx.x;
    float s = 0.f;
    for (int i = tid; i < NBLOCKS; i += 256) s += bsums[i];
#pragma unroll
    for (int off = 32; off > 0; off >>= 1)
        s += __shfl_down(s, off, 64);
    if ((tid & 63) == 0) wred[tid >> 6] = s;
    __syncthreads();
    if (tid == 0)
        out[0] = (wred[0] + wred[1] + wred[2] + wred[3]) * (1.0f / (float)NPIX);
}

extern "C" void kernel_launch(void* const* d_in, const int* in_sizes, int n_in,
                              void* d_out, int out_size, void* d_ws, size_t ws_size,
                              hipStream_t stream) {
    const float* yp = (const float*)d_in[0];
    const float* yt = (const float*)d_in[1];
    float* out = (float*)d_out;

    float* bsums = (float*)d_ws;   // 4 KB of the workspace
    sobel_loss_kernel<<<NBLOCKS, 256, 0, stream>>>(yp, yt, bsums);
    reduce_final<<<1, 256, 0, stream>>>(bsums, out);
}

// Round 4
// 150.957 us; speedup vs baseline: 1.3481x; 1.3481x over previous
//
#include <hip/hip_runtime.h>

#define IMG_W 512
#define IMG_H 512
#define BATCH 64
#define ROWS_PER_WAVE 8
#define WAVES_PER_BLOCK 4
#define ROWS_PER_BLOCK (ROWS_PER_WAVE * WAVES_PER_BLOCK)  // 32
#define SLABS (IMG_H / ROWS_PER_BLOCK)                    // 16
#define NBLOCKS (BATCH * SLABS)                           // 1024
#define NPIX (BATCH * IMG_W * IMG_H)

__device__ __forceinline__ float fast_sqrtf(float x) {
    return __builtin_amdgcn_sqrtf(x);
}

// Row-streaming Sobel, no LDS staging. One wave = 8 full rows; lane = 8-px
// strip (64 lanes x 8 = 512 = row width). 3-row rolling window kept in
// registers. R3 lesson: the rolled window loop didn't unroll -> dynamic
// slot indices -> arrays spilled to scratch (131 MB WRITE_SIZE). Fix: the
// 8 row-steps are hand-pasted macros with constant slot indices, and no
// min-waves launch bound (occupancy is grid-limited at 16 waves/CU).
__global__ __launch_bounds__(256) void sobel_loss_kernel(
    const float* __restrict__ yp, const float* __restrict__ yt,
    float* __restrict__ bsums)
{
    __shared__ float wred[WAVES_PER_BLOCK];

    const int tid  = threadIdx.x;
    const int lane = tid & 63;
    const int wv   = tid >> 6;
    const int bid  = blockIdx.x;
    const int b    = bid >> 4;            // image index (16 slabs/image)
    const int slab = bid & (SLABS - 1);
    const int y0   = slab * ROWS_PER_BLOCK + wv * ROWS_PER_WAVE;
    const int x0   = lane << 3;           // cols x0..x0+7

    const float* __restrict__ imgp = yp + (size_t)b * (IMG_W * IMG_H);
    const float* __restrict__ imgt = yt + (size_t)b * (IMG_W * IMG_H);

    // rolling raw rows: cols x0-1 .. x0+8 (10 wide) for both inputs
    float hp[3][10], ht[3][10];

    auto load_row = [&](int slot, int y) {
        float4 ap = {0.f, 0.f, 0.f, 0.f}, bp = {0.f, 0.f, 0.f, 0.f};
        float4 at = {0.f, 0.f, 0.f, 0.f}, bt = {0.f, 0.f, 0.f, 0.f};
        if (y >= 0 && y < IMG_H) {                     // wave-uniform branch
            const float* rp = imgp + (size_t)y * IMG_W + x0;
            const float* rt = imgt + (size_t)y * IMG_W + x0;
            ap = *(const float4*)rp;
            bp = *(const float4*)(rp + 4);
            at = *(const float4*)rt;
            bt = *(const float4*)(rt + 4);
        }
        // x-halo from neighbor lanes; image edge -> 0 ('SAME' zero padding)
        float lp  = __shfl_up(bp.w, 1, 64);
        float rp_ = __shfl_down(ap.x, 1, 64);
        float lt  = __shfl_up(bt.w, 1, 64);
        float rt_ = __shfl_down(at.x, 1, 64);
        if (lane == 0)  { lp = 0.f; lt = 0.f; }
        if (lane == 63) { rp_ = 0.f; rt_ = 0.f; }
        hp[slot][0] = lp;   ht[slot][0] = lt;
        hp[slot][1] = ap.x; hp[slot][2] = ap.y; hp[slot][3] = ap.z; hp[slot][4] = ap.w;
        hp[slot][5] = bp.x; hp[slot][6] = bp.y; hp[slot][7] = bp.z; hp[slot][8] = bp.w;
        ht[slot][1] = at.x; ht[slot][2] = at.y; ht[slot][3] = at.z; ht[slot][4] = at.w;
        ht[slot][5] = bt.x; ht[slot][6] = bt.y; ht[slot][7] = bt.z; ht[slot][8] = bt.w;
        hp[slot][9] = rp_;  ht[slot][9] = rt_;
    };

    float lsum = 0.f;

    // One output-row step: S0=row y-1, S1=row y, S2=row y+1 (loaded here).
#define SOBEL_STEP(S0, S1, S2, YNEXT)                                          \
    do {                                                                       \
        load_row(S2, (YNEXT));                                                 \
        float cp[10], ct[10];                                                  \
        _Pragma("unroll")                                                      \
        for (int k = 0; k < 10; ++k) {                                         \
            cp[k] = fmaf(2.f, hp[S1][k], hp[S0][k]) + hp[S2][k];               \
            ct[k] = fmaf(2.f, ht[S1][k], ht[S0][k]) + ht[S2][k];               \
        }                                                                      \
        _Pragma("unroll")                                                      \
        for (int j = 0; j < 8; ++j) {                                          \
            float tp  = fmaf(2.f, hp[S2][j + 1], hp[S2][j]) + hp[S2][j + 2];   \
            float bp_ = fmaf(2.f, hp[S0][j + 1], hp[S0][j]) + hp[S0][j + 2];   \
            float ghp = tp - bp_;                                              \
            float gvp = cp[j + 2] - cp[j];                                     \
            float magp = fast_sqrtf(fmaf(gvp, gvp, fmaf(ghp, ghp, 1e-18f)));   \
            float tt  = fmaf(2.f, ht[S2][j + 1], ht[S2][j]) + ht[S2][j + 2];   \
            float bt_ = fmaf(2.f, ht[S0][j + 1], ht[S0][j]) + ht[S0][j + 2];   \
            float ght = tt - bt_;                                              \
            float gvt = ct[j + 2] - ct[j];                                     \
            float magt = fast_sqrtf(fmaf(gvt, gvt, fmaf(ght, ght, 1e-18f)));   \
            lsum += fabsf(magt - magp);  /* == sqrt(d^2+eps)*(d^2!=0) */       \
        }                                                                      \
    } while (0)

    load_row(0, y0 - 1);
    load_row(1, y0);
    SOBEL_STEP(0, 1, 2, y0 + 1);
    SOBEL_STEP(1, 2, 0, y0 + 2);
    SOBEL_STEP(2, 0, 1, y0 + 3);
    SOBEL_STEP(0, 1, 2, y0 + 4);
    SOBEL_STEP(1, 2, 0, y0 + 5);
    SOBEL_STEP(2, 0, 1, y0 + 6);
    SOBEL_STEP(0, 1, 2, y0 + 7);
    SOBEL_STEP(1, 2, 0, y0 + 8);
#undef SOBEL_STEP

    // ---- Block reduction ----
#pragma unroll
    for (int off = 32; off > 0; off >>= 1)
        lsum += __shfl_down(lsum, off, 64);
    if (lane == 0) wred[wv] = lsum;
    __syncthreads();
    if (tid == 0)
        bsums[bid] = wred[0] + wred[1] + wred[2] + wred[3];
}

__global__ __launch_bounds__(256) void reduce_final(
    const float* __restrict__ bsums, float* __restrict__ out)
{
    __shared__ float wred[4];
    const int tid = threadIdx.x;
    float s = 0.f;
    for (int i = tid; i < NBLOCKS; i += 256) s += bsums[i];
#pragma unroll
    for (int off = 32; off > 0; off >>= 1)
        s += __shfl_down(s, off, 64);
    if ((tid & 63) == 0) wred[tid >> 6] = s;
    __syncthreads();
    if (tid == 0)
        out[0] = (wred[0] + wred[1] + wred[2] + wred[3]) * (1.0f / (float)NPIX);
}

extern "C" void kernel_launch(void* const* d_in, const int* in_sizes, int n_in,
                              void* d_out, int out_size, void* d_ws, size_t ws_size,
                              hipStream_t stream) {
    const float* yp = (const float*)d_in[0];
    const float* yt = (const float*)d_in[1];
    float* out = (float*)d_out;

    float* bsums = (float*)d_ws;   // 4 KB of the workspace
    sobel_loss_kernel<<<NBLOCKS, 256, 0, stream>>>(yp, yt, bsums);
    reduce_final<<<1, 256, 0, stream>>>(bsums, out);
}

// Round 5
// 150.058 us; speedup vs baseline: 1.3562x; 1.0060x over previous
//
#include <hip/hip_runtime.h>

#define IMG_W 512
#define IMG_H 512
#define BATCH 64
#define ROWS_PER_WAVE 8
#define SLABS (IMG_H / ROWS_PER_WAVE)        // 64 slabs/image
#define NBLOCKS (BATCH * SLABS)              // 4096 blocks, 1 wave each
#define NPIX (BATCH * IMG_W * IMG_H)

__device__ __forceinline__ float fast_sqrtf(float x) {
    return __builtin_amdgcn_sqrtf(x);
}

// Row-streaming Sobel, one wave per block (no LDS, no barriers). Lane = 8-px
// strip; 64 lanes x 8 = 512 = full row. 3-row raw window in registers.
// R4 lesson: assembling a row right after issuing its loads forces a vmcnt
// drain every step (only 1 row in flight -> latency-bound, HBM 20%).
// Fix: 2-slot register pipeline — a row is issued 2 steps before it is
// assembled, so its latency is covered by ~2 steps of compute. All array
// indices are compile-time constants (R3 spill lesson).
__global__ __launch_bounds__(64) void sobel_loss_kernel(
    const float* __restrict__ yp, const float* __restrict__ yt,
    float* __restrict__ bsums)
{
    const int lane = threadIdx.x;            // block == one wave
    const int bid  = blockIdx.x;
    const int b    = bid >> 6;               // image index (64 slabs/image)
    const int slab = bid & (SLABS - 1);
    const int y0   = slab * ROWS_PER_WAVE;
    const int x0   = lane << 3;              // cols x0..x0+7

    const float* __restrict__ imgp = yp + (size_t)b * (IMG_W * IMG_H);
    const float* __restrict__ imgt = yt + (size_t)b * (IMG_W * IMG_H);

    float hp[3][10], ht[3][10];              // rolling raw rows, cols x0-1..x0+8
    float4 A0p, B0p, A0t, B0t;               // prefetch slot 0
    float4 A1p, B1p, A1t, B1t;               // prefetch slot 1

    // Issue the 4 float4 loads of row Y into slot S (no consumption here).
#define ISSUE(S, Y)                                                            \
    do {                                                                       \
        int yy = (Y);                                                          \
        if (yy >= 0 && yy < IMG_H) {                                           \
            const float* rp = imgp + (size_t)yy * IMG_W + x0;                  \
            const float* rt = imgt + (size_t)yy * IMG_W + x0;                  \
            A##S##p = *(const float4*)rp;                                      \
            B##S##p = *(const float4*)(rp + 4);                                \
            A##S##t = *(const float4*)rt;                                      \
            B##S##t = *(const float4*)(rt + 4);                                \
        } else {                                                               \
            A##S##p = {0.f, 0.f, 0.f, 0.f}; B##S##p = {0.f, 0.f, 0.f, 0.f};   \
            A##S##t = {0.f, 0.f, 0.f, 0.f}; B##S##t = {0.f, 0.f, 0.f, 0.f};   \
        }                                                                      \
    } while (0)

    // Consume slot S (vmcnt wait lands here, 2 steps after ISSUE) -> h[R].
#define ASSEMBLE(S, R)                                                         \
    do {                                                                       \
        float lp  = __shfl_up(B##S##p.w, 1, 64);                               \
        float rp_ = __shfl_down(A##S##p.x, 1, 64);                             \
        float lt  = __shfl_up(B##S##t.w, 1, 64);                               \
        float rt_ = __shfl_down(A##S##t.x, 1, 64);                             \
        if (lane == 0)  { lp = 0.f; lt = 0.f; }                                \
        if (lane == 63) { rp_ = 0.f; rt_ = 0.f; }                              \
        hp[R][0] = lp;      ht[R][0] = lt;                                     \
        hp[R][1] = A##S##p.x; hp[R][2] = A##S##p.y;                            \
        hp[R][3] = A##S##p.z; hp[R][4] = A##S##p.w;                            \
        hp[R][5] = B##S##p.x; hp[R][6] = B##S##p.y;                            \
        hp[R][7] = B##S##p.z; hp[R][8] = B##S##p.w;                            \
        ht[R][1] = A##S##t.x; ht[R][2] = A##S##t.y;                            \
        ht[R][3] = A##S##t.z; ht[R][4] = A##S##t.w;                            \
        ht[R][5] = B##S##t.x; ht[R][6] = B##S##t.y;                            \
        ht[R][7] = B##S##t.z; ht[R][8] = B##S##t.w;                            \
        hp[R][9] = rp_;     ht[R][9] = rt_;                                    \
    } while (0)

    float lsum = 0.f;

    // One output row: S0 = y-1, S1 = y, S2 = y+1 (already assembled).
#define COMPUTE(S0, S1, S2)                                                    \
    do {                                                                       \
        float cp[10], ct[10];                                                  \
        _Pragma("unroll")                                                      \
        for (int k = 0; k < 10; ++k) {                                         \
            cp[k] = fmaf(2.f, hp[S1][k], hp[S0][k]) + hp[S2][k];               \
            ct[k] = fmaf(2.f, ht[S1][k], ht[S0][k]) + ht[S2][k];               \
        }                                                                      \
        _Pragma("unroll")                                                      \
        for (int j = 0; j < 8; ++j) {                                          \
            float tp  = fmaf(2.f, hp[S2][j + 1], hp[S2][j]) + hp[S2][j + 2];   \
            float bp_ = fmaf(2.f, hp[S0][j + 1], hp[S0][j]) + hp[S0][j + 2];   \
            float ghp = tp - bp_;                                              \
            float gvp = cp[j + 2] - cp[j];                                     \
            float magp = fast_sqrtf(fmaf(gvp, gvp, fmaf(ghp, ghp, 1e-18f)));   \
            float tt  = fmaf(2.f, ht[S2][j + 1], ht[S2][j]) + ht[S2][j + 2];   \
            float bt_ = fmaf(2.f, ht[S0][j + 1], ht[S0][j]) + ht[S0][j + 2];   \
            float ght = tt - bt_;                                              \
            float gvt = ct[j + 2] - ct[j];                                     \
            float magt = fast_sqrtf(fmaf(gvt, gvt, fmaf(ght, ght, 1e-18f)));   \
            lsum += fabsf(magt - magp); /* == sqrt(d^2+eps)*(d^2!=0) */        \
        }                                                                      \
    } while (0)

    // Prologue: rows y0-1 .. y0+2 in flight / assembled.
    ISSUE(0, y0 - 1);
    ISSUE(1, y0);
    ASSEMBLE(0, 0);  ISSUE(0, y0 + 1);
    ASSEMBLE(1, 1);  ISSUE(1, y0 + 2);

    // Steady state: assemble row issued 2 steps ago, refill slot, compute.
    ASSEMBLE(0, 2);  ISSUE(0, y0 + 3);  COMPUTE(0, 1, 2);
    ASSEMBLE(1, 0);  ISSUE(1, y0 + 4);  COMPUTE(1, 2, 0);
    ASSEMBLE(0, 1);  ISSUE(0, y0 + 5);  COMPUTE(2, 0, 1);
    ASSEMBLE(1, 2);  ISSUE(1, y0 + 6);  COMPUTE(0, 1, 2);
    ASSEMBLE(0, 0);  ISSUE(0, y0 + 7);  COMPUTE(1, 2, 0);
    ASSEMBLE(1, 1);  ISSUE(1, y0 + 8);  COMPUTE(2, 0, 1);
    ASSEMBLE(0, 2);                     COMPUTE(0, 1, 2);
    ASSEMBLE(1, 0);                     COMPUTE(1, 2, 0);

#undef ISSUE
#undef ASSEMBLE
#undef COMPUTE

    // ---- Wave reduction (block == wave, no LDS needed) ----
#pragma unroll
    for (int off = 32; off > 0; off >>= 1)
        lsum += __shfl_down(lsum, off, 64);
    if (lane == 0)
        bsums[bid] = lsum;
}

__global__ __launch_bounds__(256) void reduce_final(
    const float* __restrict__ bsums, float* __restrict__ out)
{
    __shared__ float wred[4];
    const int tid = threadIdx.x;
    float s = 0.f;
    for (int i = tid; i < NBLOCKS; i += 256) s += bsums[i];
#pragma unroll
    for (int off = 32; off > 0; off >>= 1)
        s += __shfl_down(s, off, 64);
    if ((tid & 63) == 0) wred[tid >> 6] = s;
    __syncthreads();
    if (tid == 0)
        out[0] = (wred[0] + wred[1] + wred[2] + wred[3]) * (1.0f / (float)NPIX);
}

extern "C" void kernel_launch(void* const* d_in, const int* in_sizes, int n_in,
                              void* d_out, int out_size, void* d_ws, size_t ws_size,
                              hipStream_t stream) {
    const float* yp = (const float*)d_in[0];
    const float* yt = (const float*)d_in[1];
    float* out = (float*)d_out;

    float* bsums = (float*)d_ws;   // 16 KB of workspace
    sobel_loss_kernel<<<NBLOCKS, 64, 0, stream>>>(yp, yt, bsums);
    reduce_final<<<1, 256, 0, stream>>>(bsums, out);
}